// Round 7
// baseline (243.189 us; speedup 1.0000x reference)
//
#include <hip/hip_runtime.h>

// Problem constants (B=2, S=2048, D=1024, H=16, HD=64). fp32 in / fp32 out.
#define NB 2
#define NS 2048
#define ND 1024
#define NH 16
#define NHD 64
#define QLD (3 * ND)   // qkv workspace row stride in elements = 3072
#define PADP 72        // Ps row stride (u16)
#define PADV 68        // Vt row stride (u16)

typedef unsigned short u16;
typedef __attribute__((ext_vector_type(8))) short short8;   // 8 x bf16 (4 VGPRs)
typedef __attribute__((ext_vector_type(4))) short short4v;  // 4 x bf16 (2 VGPRs)
typedef __attribute__((ext_vector_type(4))) float f32x4;

__device__ __forceinline__ u16 f2b(float f) {
    unsigned int x = __float_as_uint(f);
    return (u16)((x + 0x7fffu + ((x >> 16) & 1u)) >> 16);  // RNE
}

// ---------------------------------------------------------------------------
// fp32 -> bf16 elementwise cast (for x). n must be a multiple of 8.
__global__ __launch_bounds__(256) void convert_bf16(
    const float* __restrict__ src, u16* __restrict__ dst, int n)
{
    const int i = (blockIdx.x * 256 + threadIdx.x) * 8;
    if (i >= n) return;
    float4 a = *(const float4*)(src + i);
    float4 b = *(const float4*)(src + i + 4);
    *(ushort4*)(dst + i)     = make_ushort4(f2b(a.x), f2b(a.y), f2b(a.z), f2b(a.w));
    *(ushort4*)(dst + i + 4) = make_ushort4(f2b(b.x), f2b(b.y), f2b(b.z), f2b(b.w));
}

// ---------------------------------------------------------------------------
// W[K,N] fp32 -> WT[N,K] bf16 (64x64 tiles via LDS).
__global__ __launch_bounds__(256) void transpose_bf16(
    const float* __restrict__ W, u16* __restrict__ WT, int K, int N)
{
    __shared__ u16 Ts[64 * 72];
    const int t = threadIdx.x;
    const int k0 = blockIdx.y << 6, n0 = blockIdx.x << 6;
    const int r = t >> 4, c = (t & 15) << 2;
    #pragma unroll
    for (int rr = 0; rr < 64; rr += 16) {
        float4 v = *(const float4*)&W[(size_t)(k0 + r + rr) * N + n0 + c];
        Ts[(c + 0) * 72 + r + rr] = f2b(v.x);
        Ts[(c + 1) * 72 + r + rr] = f2b(v.y);
        Ts[(c + 2) * 72 + r + rr] = f2b(v.z);
        Ts[(c + 3) * 72 + r + rr] = f2b(v.w);
    }
    __syncthreads();
    const int n = t >> 2, cc = (t & 3) << 4;
    uint4 a = *(const uint4*)&Ts[n * 72 + cc];
    uint4 b = *(const uint4*)&Ts[n * 72 + cc + 8];
    *(uint4*)&WT[(size_t)(n0 + n) * K + k0 + cc]     = a;
    *(uint4*)&WT[(size_t)(n0 + n) * K + k0 + cc + 8] = b;
}

// ---------------------------------------------------------------------------
// bf16 MFMA GEMM (m97 structure): C[M,N] = A[M,K] @ BT[N,K]^T + bias[N].
// 128x128 tile, 256 threads, BK=32, global_load_lds w=16, XOR swizzle.
template <bool STORE_BF16>
__global__ __launch_bounds__(256) void gemm_mfma(
    const u16* __restrict__ A, const u16* __restrict__ BT,
    const float* __restrict__ bias,
    void* __restrict__ C, int M, int N, int K)
{
    __shared__ u16 As[128 * 32];
    __shared__ u16 Bs[128 * 32];

    const int tid = threadIdx.x;
    const int wave = tid >> 6, lane = tid & 63;
    const int col = lane & 15, quad = lane >> 4;
    const int wm = wave >> 1, wn = wave & 1;
    const int row0 = blockIdx.y << 7, col0 = blockIdx.x << 7;

    f32x4 acc[4][4] = {};

    const u16* asrc[2];
    const u16* bsrc[2];
    u16* adst[2];
    u16* bdst[2];
    #pragma unroll
    for (int is = 0; is < 2; ++is) {
        const int J = is * 256 + wave * 64 + lane;
        const int m = J >> 2;
        const int q = (J & 3) ^ ((m >> 1) & 3);
        asrc[is] = A  + (size_t)(row0 + m) * K + q * 8;
        bsrc[is] = BT + (size_t)(col0 + m) * K + q * 8;
        adst[is] = &As[(size_t)(is * 256 + wave * 64) * 8];
        bdst[is] = &Bs[(size_t)(is * 256 + wave * 64) * 8];
    }

    for (int kk = 0; kk < K; kk += 32) {
        __syncthreads();
        #pragma unroll
        for (int is = 0; is < 2; ++is) {
            __builtin_amdgcn_global_load_lds(
                (const __attribute__((address_space(1))) unsigned int*)(asrc[is] + kk),
                (__attribute__((address_space(3))) unsigned int*)adst[is], 16, 0, 0);
            __builtin_amdgcn_global_load_lds(
                (const __attribute__((address_space(1))) unsigned int*)(bsrc[is] + kk),
                (__attribute__((address_space(3))) unsigned int*)bdst[is], 16, 0, 0);
        }
        __syncthreads();

        short8 af[4], bf[4];
        #pragma unroll
        for (int i = 0; i < 4; ++i) {
            const int m = wm * 64 + i * 16 + col;
            af[i] = *(const short8*)&As[(m * 4 + (quad ^ ((m >> 1) & 3))) * 8];
        }
        #pragma unroll
        for (int j = 0; j < 4; ++j) {
            const int n = wn * 64 + j * 16 + col;
            bf[j] = *(const short8*)&Bs[(n * 4 + (quad ^ ((n >> 1) & 3))) * 8];
        }
        #pragma unroll
        for (int i = 0; i < 4; ++i)
            #pragma unroll
            for (int j = 0; j < 4; ++j)
                acc[i][j] = __builtin_amdgcn_mfma_f32_16x16x32_bf16(
                    af[i], bf[j], acc[i][j], 0, 0, 0);
    }

    #pragma unroll
    for (int j = 0; j < 4; ++j) {
        const int gc = col0 + wn * 64 + j * 16 + col;
        const float bj = bias[gc];
        #pragma unroll
        for (int i = 0; i < 4; ++i) {
            const int gr = row0 + wm * 64 + i * 16 + quad * 4;
            #pragma unroll
            for (int r = 0; r < 4; ++r) {
                const float v = acc[i][j][r] + bj;
                if (STORE_BF16)
                    ((u16*)C)[(size_t)(gr + r) * N + gc] = f2b(v);
                else
                    ((float*)C)[(size_t)(gr + r) * N + gc] = v;
            }
        }
    }
}

// ---------------------------------------------------------------------------
// MFMA flash attention, transposed-S form.
// Block = (qt, bh): one 64-query tile; qt = 31 - blockIdx.x (big blocks
// dispatch first to kill the causal tail). 4 waves x 16-query strips.
// S^T = K_tile @ Q^T via mfma(A=K-frag, B=Q-frag): C-layout gives each lane
// ONE query (q = q0+col) and 16 k-values in registers -> softmax is
// in-register reduce + 2 shuffles (xor 16,32); m,l are per-lane scalars.
// O^T = V^T @ P^T via mfma(A=Vt-frag, B=P-frag from the Ps round-trip).
__global__ __launch_bounds__(256) void attn_kernel(
    const u16* __restrict__ qkv, u16* __restrict__ vals)
{
    __shared__ u16 Ks[64 * 64];     // 8 KB, XOR-swizzled 16B chunks (Q, then K)
    __shared__ u16 Vt[64 * PADV];   // 8.5 KB, transposed V
    __shared__ u16 Ps[64 * PADP];   // 9 KB, per-wave 16-row strips

    const int tid = threadIdx.x;
    const int wave = tid >> 6, lane = tid & 63;
    const int col = lane & 15, quad = lane >> 4;
    const int qt = 31 - blockIdx.x;      // big-first
    const int bh = blockIdx.y;
    const int b = bh >> 4, h = bh & 15;
    const size_t base = (size_t)b * NS * QLD + (size_t)h * (3 * NHD);
    const int q0 = wave * 16;
    const int qloc = q0 + col;           // this lane's query (tile-local)

    // DMA decomposition: J = is*256 + wave*64 + lane; row m=J>>3, stored
    // chunk position c'=J&7 holds source chunk c = c' ^ (m&7).
    int Jrow[2], Jcol[2];
    #pragma unroll
    for (int is = 0; is < 2; ++is) {
        const int J = is * 256 + wave * 64 + lane;
        Jrow[is] = J >> 3;
        Jcol[is] = ((J & 7) ^ (Jrow[is] & 7)) << 3;
    }

    auto stage_tile = [&](int srow, int coloff) {
        #pragma unroll
        for (int is = 0; is < 2; ++is) {
            __builtin_amdgcn_global_load_lds(
                (const __attribute__((address_space(1))) unsigned int*)
                    (qkv + base + (size_t)(srow + Jrow[is]) * QLD + coloff + Jcol[is]),
                (__attribute__((address_space(3))) unsigned int*)
                    &Ks[(size_t)(is * 256 + wave * 64) * 8], 16, 0, 0);
        }
    };
    // fragment read from swizzled Ks: row, k-half (reads row, d=half*32+quad*8..+7)
    auto read_frag = [&](int row, int half) -> short8 {
        const int blk = row * 8 + ((quad + (half << 2)) ^ (row & 7));
        return *(const short8*)&Ks[blk << 3];
    };

    // ---- prologue: stage Q tile, hoist Q B-fragments ----
    stage_tile(qt * 64, 0);
    __syncthreads();
    short8 bq0 = read_frag(qloc, 0);
    short8 bq1 = read_frag(qloc, 1);

    f32x4 accO[4] = {};                  // O^T accumulator (rows=d, col=q)
    float m = -1e30f, l = 0.f;

    const int vtx = tid & 15, vty = tid >> 4;
    const int vk0 = vty << 2, vd0 = vtx << 2;

    for (int kt = 0; kt <= qt; ++kt) {
        __syncthreads();                 // Q-frag reads (kt=0) / prior tile reads done
        stage_tile(kt * 64, NHD);        // K tile -> Ks (async DMA)
        {   // V tile -> Vt transposed (4x4 register transpose)
            const u16* vsrc = qkv + base + (size_t)(kt * 64 + vk0) * QLD + 2 * NHD + vd0;
            ushort4 r0 = *(const ushort4*)(vsrc);
            ushort4 r1 = *(const ushort4*)(vsrc + QLD);
            ushort4 r2 = *(const ushort4*)(vsrc + 2 * QLD);
            ushort4 r3 = *(const ushort4*)(vsrc + 3 * QLD);
            *(ushort4*)&Vt[(vd0 + 0) * PADV + vk0] = make_ushort4(r0.x, r1.x, r2.x, r3.x);
            *(ushort4*)&Vt[(vd0 + 1) * PADV + vk0] = make_ushort4(r0.y, r1.y, r2.y, r3.y);
            *(ushort4*)&Vt[(vd0 + 2) * PADV + vk0] = make_ushort4(r0.z, r1.z, r2.z, r3.z);
            *(ushort4*)&Vt[(vd0 + 3) * PADV + vk0] = make_ushort4(r0.w, r1.w, r2.w, r3.w);
        }
        __syncthreads();                 // DMA + Vt writes visible

        // ---- S^T = K Q^T : lane gets s for q=qloc, k = kg*16+quad*4+r ----
        f32x4 s[4] = {};
        #pragma unroll
        for (int kg = 0; kg < 4; ++kg) {
            short8 af0 = read_frag(kg * 16 + col, 0);
            short8 af1 = read_frag(kg * 16 + col, 1);
            s[kg] = __builtin_amdgcn_mfma_f32_16x16x32_bf16(af0, bq0, s[kg], 0, 0, 0);
            s[kg] = __builtin_amdgcn_mfma_f32_16x16x32_bf16(af1, bq1, s[kg], 0, 0, 0);
        }

        // ---- scale + causal mask (diagonal tile only) ----
        const bool diag = (kt == qt);
        #pragma unroll
        for (int kg = 0; kg < 4; ++kg)
            #pragma unroll
            for (int r = 0; r < 4; ++r) {
                float v = s[kg][r] * 0.125f;
                if (diag && (kg * 16 + quad * 4 + r > qloc)) v = -1e30f;
                s[kg][r] = v;
            }

        // ---- online softmax: in-register reduce + 2 shuffles ----
        float mx = -1e30f;
        #pragma unroll
        for (int kg = 0; kg < 4; ++kg) {
            float a = fmaxf(fmaxf(s[kg][0], s[kg][1]), fmaxf(s[kg][2], s[kg][3]));
            mx = fmaxf(mx, a);
        }
        mx = fmaxf(mx, __shfl_xor(mx, 16, 64));
        mx = fmaxf(mx, __shfl_xor(mx, 32, 64));
        const float mn = fmaxf(m, mx);
        const float alpha = __expf(m - mn);
        m = mn;

        float ps = 0.f;
        #pragma unroll
        for (int kg = 0; kg < 4; ++kg)
            #pragma unroll
            for (int r = 0; r < 4; ++r) {
                const float p = __expf(s[kg][r] - mn);
                ps += p;
                Ps[qloc * PADP + kg * 16 + quad * 4 + r] = f2b(p);
            }
        ps += __shfl_xor(ps, 16, 64);
        ps += __shfl_xor(ps, 32, 64);
        l = l * alpha + ps;
        #pragma unroll
        for (int dg = 0; dg < 4; ++dg)
            #pragma unroll
            for (int r = 0; r < 4; ++r) accO[dg][r] *= alpha;

        // ---- O^T += V^T P^T (Ps strip is wave-private; lgkm wait only) ----
        short8 pb0 = *(const short8*)&Ps[qloc * PADP + quad * 8];
        short8 pb1 = *(const short8*)&Ps[qloc * PADP + 32 + quad * 8];
        #pragma unroll
        for (int dg = 0; dg < 4; ++dg) {
            const int n = dg * 16 + col;
            short4v lo0 = *(const short4v*)&Vt[n * PADV + quad * 8];
            short4v hi0 = *(const short4v*)&Vt[n * PADV + quad * 8 + 4];
            short4v lo1 = *(const short4v*)&Vt[n * PADV + 32 + quad * 8];
            short4v hi1 = *(const short4v*)&Vt[n * PADV + 32 + quad * 8 + 4];
            short8 vb0 = __builtin_shufflevector(lo0, hi0, 0, 1, 2, 3, 4, 5, 6, 7);
            short8 vb1 = __builtin_shufflevector(lo1, hi1, 0, 1, 2, 3, 4, 5, 6, 7);
            accO[dg] = __builtin_amdgcn_mfma_f32_16x16x32_bf16(vb0, pb0, accO[dg], 0, 0, 0);
            accO[dg] = __builtin_amdgcn_mfma_f32_16x16x32_bf16(vb1, pb1, accO[dg], 0, 0, 0);
        }
    }

    // ---- epilogue: vals[b][q][h*64+d] = O / l; O^T rows d=dg*16+quad*4+r ----
    const float inv = 1.f / l;
    const size_t rowoff = ((size_t)b * NS + qt * 64 + qloc) * ND + h * NHD;
    #pragma unroll
    for (int dg = 0; dg < 4; ++dg) {
        ushort4 o;
        o.x = f2b(accO[dg][0] * inv);
        o.y = f2b(accO[dg][1] * inv);
        o.z = f2b(accO[dg][2] * inv);
        o.w = f2b(accO[dg][3] * inv);
        *(ushort4*)(vals + rowoff + dg * 16 + quad * 4) = o;
    }
}

extern "C" void kernel_launch(void* const* d_in, const int* in_sizes, int n_in,
                              void* d_out, int out_size, void* d_ws, size_t ws_size,
                              hipStream_t stream)
{
    // inputs: x, mask(unused), W_qkv, b_qkv, W_o, b_o  -- all fp32
    const float* x    = (const float*)d_in[0];
    const float* Wqkv = (const float*)d_in[2];
    const float* bqkv = (const float*)d_in[3];
    const float* Wo   = (const float*)d_in[4];
    const float* bo   = (const float*)d_in[5];
    float* out = (float*)d_out;

    u16* x_bf   = (u16*)d_ws;                       //  4096*1024
    u16* WqkvT  = x_bf   + (size_t)4096 * 1024;     //  3072*1024  [N,K]
    u16* WoT    = WqkvT  + (size_t)3072 * 1024;     //  1024*1024  [N,K]
    u16* qkv    = WoT    + (size_t)1024 * 1024;     //  4096*3072
    u16* vals   = qkv    + (size_t)4096 * 3072;     //  4096*1024

    const int M = NB * NS;  // 4096

    convert_bf16<<<dim3(M * ND / (256 * 8)), dim3(256), 0, stream>>>(
        x, x_bf, M * ND);
    transpose_bf16<<<dim3(QLD / 64, ND / 64), dim3(256), 0, stream>>>(
        Wqkv, WqkvT, ND, QLD);
    transpose_bf16<<<dim3(ND / 64, ND / 64), dim3(256), 0, stream>>>(
        Wo, WoT, ND, ND);

    gemm_mfma<true><<<dim3(QLD / 128, M / 128), dim3(256), 0, stream>>>(
        x_bf, WqkvT, bqkv, qkv, M, QLD, ND);
    attn_kernel<<<dim3(32, NB * NH), dim3(256), 0, stream>>>(qkv, vals);
    gemm_mfma<false><<<dim3(ND / 128, M / 128), dim3(256), 0, stream>>>(
        vals, WoT, bo, out, M, ND, ND);
}

// Round 8
// 219.909 us; speedup vs baseline: 1.1059x; 1.1059x over previous
//
#include <hip/hip_runtime.h>

// Problem constants (B=2, S=2048, D=1024, H=16, HD=64). fp32 in / fp32 out.
#define NB 2
#define NS 2048
#define ND 1024
#define NH 16
#define NHD 64
#define QLD (3 * ND)   // qkv workspace row stride in elements = 3072
#define PADP 72        // Ps row stride (u16); 144 B = 16B-aligned rows
#define PADV 68        // Vt row stride (u16)

typedef unsigned short u16;
typedef __attribute__((ext_vector_type(8))) short short8;   // 8 x bf16 (4 VGPRs)
typedef __attribute__((ext_vector_type(4))) short short4v;  // 4 x bf16 (2 VGPRs)
typedef __attribute__((ext_vector_type(4))) float f32x4;

__device__ __forceinline__ u16 f2b(float f) {
    unsigned int x = __float_as_uint(f);
    return (u16)((x + 0x7fffu + ((x >> 16) & 1u)) >> 16);  // RNE
}

// ---------------------------------------------------------------------------
// fp32 -> bf16 elementwise cast (for x). n must be a multiple of 8.
__global__ __launch_bounds__(256) void convert_bf16(
    const float* __restrict__ src, u16* __restrict__ dst, int n)
{
    const int i = (blockIdx.x * 256 + threadIdx.x) * 8;
    if (i >= n) return;
    float4 a = *(const float4*)(src + i);
    float4 b = *(const float4*)(src + i + 4);
    *(ushort4*)(dst + i)     = make_ushort4(f2b(a.x), f2b(a.y), f2b(a.z), f2b(a.w));
    *(ushort4*)(dst + i + 4) = make_ushort4(f2b(b.x), f2b(b.y), f2b(b.z), f2b(b.w));
}

// ---------------------------------------------------------------------------
// W[K,N] fp32 -> WT[N,K] bf16 (64x64 tiles via LDS).
__global__ __launch_bounds__(256) void transpose_bf16(
    const float* __restrict__ W, u16* __restrict__ WT, int K, int N)
{
    __shared__ u16 Ts[64 * 72];
    const int t = threadIdx.x;
    const int k0 = blockIdx.y << 6, n0 = blockIdx.x << 6;
    const int r = t >> 4, c = (t & 15) << 2;
    #pragma unroll
    for (int rr = 0; rr < 64; rr += 16) {
        float4 v = *(const float4*)&W[(size_t)(k0 + r + rr) * N + n0 + c];
        Ts[(c + 0) * 72 + r + rr] = f2b(v.x);
        Ts[(c + 1) * 72 + r + rr] = f2b(v.y);
        Ts[(c + 2) * 72 + r + rr] = f2b(v.z);
        Ts[(c + 3) * 72 + r + rr] = f2b(v.w);
    }
    __syncthreads();
    const int n = t >> 2, cc = (t & 3) << 4;
    uint4 a = *(const uint4*)&Ts[n * 72 + cc];
    uint4 b = *(const uint4*)&Ts[n * 72 + cc + 8];
    *(uint4*)&WT[(size_t)(n0 + n) * K + k0 + cc]     = a;
    *(uint4*)&WT[(size_t)(n0 + n) * K + k0 + cc + 8] = b;
}

// ---------------------------------------------------------------------------
// bf16 MFMA GEMM (m97 structure): C[M,N] = A[M,K] @ BT[N,K]^T + bias[N].
// 128x128 tile, 256 threads, BK=32, global_load_lds w=16, XOR swizzle.
template <bool STORE_BF16>
__global__ __launch_bounds__(256) void gemm_mfma(
    const u16* __restrict__ A, const u16* __restrict__ BT,
    const float* __restrict__ bias,
    void* __restrict__ C, int M, int N, int K)
{
    __shared__ u16 As[128 * 32];
    __shared__ u16 Bs[128 * 32];

    const int tid = threadIdx.x;
    const int wave = tid >> 6, lane = tid & 63;
    const int col = lane & 15, quad = lane >> 4;
    const int wm = wave >> 1, wn = wave & 1;
    const int row0 = blockIdx.y << 7, col0 = blockIdx.x << 7;

    f32x4 acc[4][4] = {};

    const u16* asrc[2];
    const u16* bsrc[2];
    u16* adst[2];
    u16* bdst[2];
    #pragma unroll
    for (int is = 0; is < 2; ++is) {
        const int J = is * 256 + wave * 64 + lane;
        const int m = J >> 2;
        const int q = (J & 3) ^ ((m >> 1) & 3);
        asrc[is] = A  + (size_t)(row0 + m) * K + q * 8;
        bsrc[is] = BT + (size_t)(col0 + m) * K + q * 8;
        adst[is] = &As[(size_t)(is * 256 + wave * 64) * 8];
        bdst[is] = &Bs[(size_t)(is * 256 + wave * 64) * 8];
    }

    for (int kk = 0; kk < K; kk += 32) {
        __syncthreads();
        #pragma unroll
        for (int is = 0; is < 2; ++is) {
            __builtin_amdgcn_global_load_lds(
                (const __attribute__((address_space(1))) unsigned int*)(asrc[is] + kk),
                (__attribute__((address_space(3))) unsigned int*)adst[is], 16, 0, 0);
            __builtin_amdgcn_global_load_lds(
                (const __attribute__((address_space(1))) unsigned int*)(bsrc[is] + kk),
                (__attribute__((address_space(3))) unsigned int*)bdst[is], 16, 0, 0);
        }
        __syncthreads();

        short8 af[4], bf[4];
        #pragma unroll
        for (int i = 0; i < 4; ++i) {
            const int m = wm * 64 + i * 16 + col;
            af[i] = *(const short8*)&As[(m * 4 + (quad ^ ((m >> 1) & 3))) * 8];
        }
        #pragma unroll
        for (int j = 0; j < 4; ++j) {
            const int n = wn * 64 + j * 16 + col;
            bf[j] = *(const short8*)&Bs[(n * 4 + (quad ^ ((n >> 1) & 3))) * 8];
        }
        #pragma unroll
        for (int i = 0; i < 4; ++i)
            #pragma unroll
            for (int j = 0; j < 4; ++j)
                acc[i][j] = __builtin_amdgcn_mfma_f32_16x16x32_bf16(
                    af[i], bf[j], acc[i][j], 0, 0, 0);
    }

    #pragma unroll
    for (int j = 0; j < 4; ++j) {
        const int gc = col0 + wn * 64 + j * 16 + col;
        const float bj = bias[gc];
        #pragma unroll
        for (int i = 0; i < 4; ++i) {
            const int gr = row0 + wm * 64 + i * 16 + quad * 4;
            #pragma unroll
            for (int r = 0; r < 4; ++r) {
                const float v = acc[i][j][r] + bj;
                if (STORE_BF16)
                    ((u16*)C)[(size_t)(gr + r) * N + gc] = f2b(v);
                else
                    ((float*)C)[(size_t)(gr + r) * N + gc] = v;
            }
        }
    }
}

// ---------------------------------------------------------------------------
// MFMA flash attention: causal pairing + transposed-S softmax + K/V prefetch.
// Block = (pair, bh): query tiles qtA=pair (0..15), qtB=31-pair (16..31);
// K/V staged once per kt, shared by both q-tiles (uniform 33 process/block).
// S^T = K @ Q^T (A=K-frag, B=Q-frag): each lane owns ONE query (qloc=q0+col)
// and 16 k-values in registers -> per-lane m,l; reduce = 2 shuffles.
// O^T = V^T @ P^T (A=Vt-frag, B=P-frag via wave-private Ps round-trip).
// K(kt+1) DMA issued after barrier B of phase kt -> drained a full compute
// phase later at barrier A of phase kt+1.
__global__ __launch_bounds__(256) void attn_kernel(
    const u16* __restrict__ qkv, u16* __restrict__ vals)
{
    __shared__ u16 Ks[2][64 * 64];    // 2 x 8 KB, XOR-swizzled 16B chunks
    __shared__ u16 Vt[2][64 * PADV];  // 2 x 8.5 KB, transposed V
    __shared__ u16 Ps[64 * PADP];     // 9 KB, per-wave 16-row strips

    const int tid = threadIdx.x;
    const int wave = tid >> 6, lane = tid & 63;
    const int col = lane & 15, quad = lane >> 4;
    const int qtA = blockIdx.x;          // 0..15
    const int qtB = 31 - qtA;            // 16..31
    const int bh = blockIdx.y;
    const int b = bh >> 4, h = bh & 15;
    const size_t base = (size_t)b * NS * QLD + (size_t)h * (3 * NHD);
    const int q0 = wave * 16;
    const int qloc = q0 + col;           // this lane's query (tile-local)

    // DMA decomposition: J = is*256 + wave*64 + lane; row m=J>>3, stored
    // chunk position c'=J&7 holds source chunk c = c' ^ (m&7).
    int Jrow[2], Jcol[2];
    #pragma unroll
    for (int is = 0; is < 2; ++is) {
        const int J = is * 256 + wave * 64 + lane;
        Jrow[is] = J >> 3;
        Jcol[is] = ((J & 7) ^ (Jrow[is] & 7)) << 3;
    }

    auto stage_tile = [&](int buf, int srow, int coloff) {
        #pragma unroll
        for (int is = 0; is < 2; ++is) {
            __builtin_amdgcn_global_load_lds(
                (const __attribute__((address_space(1))) unsigned int*)
                    (qkv + base + (size_t)(srow + Jrow[is]) * QLD + coloff + Jcol[is]),
                (__attribute__((address_space(3))) unsigned int*)
                    &Ks[buf][(size_t)(is * 256 + wave * 64) * 8], 16, 0, 0);
        }
    };
    // fragment read from swizzled Ks[buf]: row, d-half -> (row, half*32+quad*8..+7)
    auto read_frag = [&](int buf, int row, int half) -> short8 {
        const int blk = row * 8 + ((quad + (half << 2)) ^ (row & 7));
        return *(const short8*)&Ks[buf][blk << 3];
    };

    // V prefetch lanes
    const int vtx = tid & 15, vty = tid >> 4;
    const int vk0 = vty << 2, vd0 = vtx << 2;
    auto load_vregs = [&](int kt, ushort4* vr) {
        const u16* vsrc = qkv + base + (size_t)(kt * 64 + vk0) * QLD + 2 * NHD + vd0;
        vr[0] = *(const ushort4*)(vsrc);
        vr[1] = *(const ushort4*)(vsrc + QLD);
        vr[2] = *(const ushort4*)(vsrc + 2 * QLD);
        vr[3] = *(const ushort4*)(vsrc + 3 * QLD);
    };
    auto write_vt = [&](int buf, const ushort4* vr) {
        *(ushort4*)&Vt[buf][(vd0 + 0) * PADV + vk0] =
            make_ushort4(vr[0].x, vr[1].x, vr[2].x, vr[3].x);
        *(ushort4*)&Vt[buf][(vd0 + 1) * PADV + vk0] =
            make_ushort4(vr[0].y, vr[1].y, vr[2].y, vr[3].y);
        *(ushort4*)&Vt[buf][(vd0 + 2) * PADV + vk0] =
            make_ushort4(vr[0].z, vr[1].z, vr[2].z, vr[3].z);
        *(ushort4*)&Vt[buf][(vd0 + 3) * PADV + vk0] =
            make_ushort4(vr[0].w, vr[1].w, vr[2].w, vr[3].w);
    };

    // ---- prologue: stage Q_A -> Ks[0], Q_B -> Ks[1]; hoist B-fragments ----
    stage_tile(0, qtA * 64, 0);
    stage_tile(1, qtB * 64, 0);
    __syncthreads();
    short8 bqA0 = read_frag(0, qloc, 0), bqA1 = read_frag(0, qloc, 1);
    short8 bqB0 = read_frag(1, qloc, 0), bqB1 = read_frag(1, qloc, 1);
    __syncthreads();                     // Q reads done before K(0) overwrites

    f32x4 accA[4] = {}, accB[4] = {};
    float mA = -1e30f, lA = 0.f, mB = -1e30f, lB = 0.f;

    auto process = [&](const short8& b0, const short8& b1,
                       short8 (*kb)[2], short8 (*vb)[2],
                       f32x4* accO, float& m, float& l, bool diag) {
        // S^T: lane gets s for q=qloc, k = kg*16 + quad*4 + r
        f32x4 s[4] = {};
        #pragma unroll
        for (int kg = 0; kg < 4; ++kg) {
            s[kg] = __builtin_amdgcn_mfma_f32_16x16x32_bf16(kb[kg][0], b0, s[kg], 0, 0, 0);
            s[kg] = __builtin_amdgcn_mfma_f32_16x16x32_bf16(kb[kg][1], b1, s[kg], 0, 0, 0);
        }
        #pragma unroll
        for (int kg = 0; kg < 4; ++kg)
            #pragma unroll
            for (int r = 0; r < 4; ++r) {
                float v = s[kg][r] * 0.125f;
                if (diag && (kg * 16 + quad * 4 + r > qloc)) v = -1e30f;
                s[kg][r] = v;
            }
        // per-lane online softmax: in-register reduce + 2 shuffles
        float mx = -1e30f;
        #pragma unroll
        for (int kg = 0; kg < 4; ++kg)
            mx = fmaxf(mx, fmaxf(fmaxf(s[kg][0], s[kg][1]), fmaxf(s[kg][2], s[kg][3])));
        mx = fmaxf(mx, __shfl_xor(mx, 16, 64));
        mx = fmaxf(mx, __shfl_xor(mx, 32, 64));
        const float mn = fmaxf(m, mx);
        const float alpha = __expf(m - mn);
        m = mn;

        float ps = 0.f;
        #pragma unroll
        for (int kg = 0; kg < 4; ++kg) {
            float p0 = __expf(s[kg][0] - mn);
            float p1 = __expf(s[kg][1] - mn);
            float p2 = __expf(s[kg][2] - mn);
            float p3 = __expf(s[kg][3] - mn);
            ps += (p0 + p1) + (p2 + p3);
            *(ushort4*)&Ps[qloc * PADP + kg * 16 + quad * 4] =
                make_ushort4(f2b(p0), f2b(p1), f2b(p2), f2b(p3));
        }
        ps += __shfl_xor(ps, 16, 64);
        ps += __shfl_xor(ps, 32, 64);
        l = l * alpha + ps;
        #pragma unroll
        for (int dg = 0; dg < 4; ++dg)
            #pragma unroll
            for (int r = 0; r < 4; ++r) accO[dg][r] *= alpha;

        // O^T += V^T P^T  (Ps strip wave-private; lgkm wait only)
        short8 pb0 = *(const short8*)&Ps[qloc * PADP + quad * 8];
        short8 pb1 = *(const short8*)&Ps[qloc * PADP + 32 + quad * 8];
        #pragma unroll
        for (int dg = 0; dg < 4; ++dg) {
            accO[dg] = __builtin_amdgcn_mfma_f32_16x16x32_bf16(vb[dg][0], pb0, accO[dg], 0, 0, 0);
            accO[dg] = __builtin_amdgcn_mfma_f32_16x16x32_bf16(vb[dg][1], pb1, accO[dg], 0, 0, 0);
        }
    };

    // ---- software pipeline ----
    ushort4 vcur[4], vnxt[4];
    stage_tile(0, 0, NHD);               // K(0) -> Ks[0]
    load_vregs(0, vcur);

    for (int kt = 0; kt <= qtB; ++kt) {
        const int cur = kt & 1, nxt = cur ^ 1;
        __syncthreads();                 // (A) drains K(kt) DMA (aged a phase)
        write_vt(cur, vcur);
        __syncthreads();                 // (B) Vt[cur] visible
        if (kt < qtB) {
            stage_tile(nxt, (kt + 1) * 64, NHD);  // in flight during compute
            load_vregs(kt + 1, vnxt);
        }

        // read K/V fragments once, reuse for both q-tiles
        short8 kb[4][2], vb[4][2];
        #pragma unroll
        for (int kg = 0; kg < 4; ++kg) {
            kb[kg][0] = read_frag(cur, kg * 16 + col, 0);
            kb[kg][1] = read_frag(cur, kg * 16 + col, 1);
        }
        #pragma unroll
        for (int dg = 0; dg < 4; ++dg) {
            const int n = dg * 16 + col;
            short4v lo0 = *(const short4v*)&Vt[cur][n * PADV + quad * 8];
            short4v hi0 = *(const short4v*)&Vt[cur][n * PADV + quad * 8 + 4];
            short4v lo1 = *(const short4v*)&Vt[cur][n * PADV + 32 + quad * 8];
            short4v hi1 = *(const short4v*)&Vt[cur][n * PADV + 32 + quad * 8 + 4];
            vb[dg][0] = __builtin_shufflevector(lo0, hi0, 0, 1, 2, 3, 4, 5, 6, 7);
            vb[dg][1] = __builtin_shufflevector(lo1, hi1, 0, 1, 2, 3, 4, 5, 6, 7);
        }

        process(bqB0, bqB1, kb, vb, accB, mB, lB, kt == qtB);
        if (kt <= qtA)
            process(bqA0, bqA1, kb, vb, accA, mA, lA, kt == qtA);

        #pragma unroll
        for (int i = 0; i < 4; ++i) vcur[i] = vnxt[i];
    }

    // ---- epilogue: O^T rows d = dg*16 + quad*4 + r, query qloc ----
    {
        const float inv = 1.f / lA;
        const size_t rowoff = ((size_t)b * NS + qtA * 64 + qloc) * ND + h * NHD;
        #pragma unroll
        for (int dg = 0; dg < 4; ++dg) {
            ushort4 o;
            o.x = f2b(accA[dg][0] * inv);
            o.y = f2b(accA[dg][1] * inv);
            o.z = f2b(accA[dg][2] * inv);
            o.w = f2b(accA[dg][3] * inv);
            *(ushort4*)(vals + rowoff + dg * 16 + quad * 4) = o;
        }
    }
    {
        const float inv = 1.f / lB;
        const size_t rowoff = ((size_t)b * NS + qtB * 64 + qloc) * ND + h * NHD;
        #pragma unroll
        for (int dg = 0; dg < 4; ++dg) {
            ushort4 o;
            o.x = f2b(accB[dg][0] * inv);
            o.y = f2b(accB[dg][1] * inv);
            o.z = f2b(accB[dg][2] * inv);
            o.w = f2b(accB[dg][3] * inv);
            *(ushort4*)(vals + rowoff + dg * 16 + quad * 4) = o;
        }
    }
}

extern "C" void kernel_launch(void* const* d_in, const int* in_sizes, int n_in,
                              void* d_out, int out_size, void* d_ws, size_t ws_size,
                              hipStream_t stream)
{
    // inputs: x, mask(unused), W_qkv, b_qkv, W_o, b_o  -- all fp32
    const float* x    = (const float*)d_in[0];
    const float* Wqkv = (const float*)d_in[2];
    const float* bqkv = (const float*)d_in[3];
    const float* Wo   = (const float*)d_in[4];
    const float* bo   = (const float*)d_in[5];
    float* out = (float*)d_out;

    u16* x_bf   = (u16*)d_ws;                       //  4096*1024
    u16* WqkvT  = x_bf   + (size_t)4096 * 1024;     //  3072*1024  [N,K]
    u16* WoT    = WqkvT  + (size_t)3072 * 1024;     //  1024*1024  [N,K]
    u16* qkv    = WoT    + (size_t)1024 * 1024;     //  4096*3072
    u16* vals   = qkv    + (size_t)4096 * 3072;     //  4096*1024

    const int M = NB * NS;  // 4096

    convert_bf16<<<dim3(M * ND / (256 * 8)), dim3(256), 0, stream>>>(
        x, x_bf, M * ND);
    transpose_bf16<<<dim3(QLD / 64, ND / 64), dim3(256), 0, stream>>>(
        Wqkv, WqkvT, ND, QLD);
    transpose_bf16<<<dim3(ND / 64, ND / 64), dim3(256), 0, stream>>>(
        Wo, WoT, ND, ND);

    gemm_mfma<true><<<dim3(QLD / 128, M / 128), dim3(256), 0, stream>>>(
        x_bf, WqkvT, bqkv, qkv, M, QLD, ND);
    attn_kernel<<<dim3(16, NB * NH), dim3(256), 0, stream>>>(qkv, vals);
    gemm_mfma<false><<<dim3(ND / 128, M / 128), dim3(256), 0, stream>>>(
        vals, WoT, bo, out, M, ND, ND);
}